// Round 4
// baseline (692.708 us; speedup 1.0000x reference)
//
#include <hip/hip_runtime.h>

typedef __bf16 bf16_t;
typedef bf16_t bf16x8 __attribute__((ext_vector_type(8)));
typedef bf16_t bf16x4 __attribute__((ext_vector_type(4)));
typedef float f32x4 __attribute__((ext_vector_type(4)));
typedef float f32x16 __attribute__((ext_vector_type(16)));

#define F 512
#define NLAYERS 8
#define NLIL 8
#define TM 128

// ---- merged prepass: blocks 0..511 transpose Wbig -> bf16 [g][f];
//      blocks 512..1023 convert Wlil fp32 -> bf16 (already [m][g][f] = B^T)
__global__ void prep_w(const float* __restrict__ Wbig, const float* __restrict__ Wlil,
                       bf16_t* __restrict__ WbigT, bf16_t* __restrict__ WlilB) {
  const int b = blockIdx.x;
  const int tid = threadIdx.x;
  if (b < 512) {
    __shared__ float tile[64][65];
    const int l = b >> 6, tf = (b >> 3) & 7, tg = b & 7;
    const float* Wl = Wbig + (size_t)l * F * F;
    bf16_t* Ol = WbigT + (size_t)l * F * F;
    const int tx = tid & 63, ty = tid >> 6;
#pragma unroll
    for (int i = 0; i < 16; ++i) {
      int f = i * 4 + ty;
      tile[f][tx] = Wl[(size_t)(tf * 64 + f) * F + tg * 64 + tx];
    }
    __syncthreads();
#pragma unroll
    for (int i = 0; i < 16; ++i) {
      int g = i * 4 + ty;
      Ol[(size_t)(tg * 64 + g) * F + tf * 64 + tx] = (bf16_t)tile[tx][g];
    }
  } else {
    const int cb = b - 512;  // 0..511, each handles 4096 bf16x8 groups
    const float4* in = (const float4*)Wlil;
    bf16x8* out8 = (bf16x8*)WlilB;
#pragma unroll
    for (int i = 0; i < 16; ++i) {
      int idx = (cb * 16 + i) * 256 + tid;  // 0..2097151
      float4 u = in[(size_t)idx * 2];
      float4 v = in[(size_t)idx * 2 + 1];
      bf16x8 t;
      t[0] = (bf16_t)u.x; t[1] = (bf16_t)u.y; t[2] = (bf16_t)u.z; t[3] = (bf16_t)u.w;
      t[4] = (bf16_t)v.x; t[5] = (bf16_t)v.y; t[6] = (bf16_t)v.z; t[7] = (bf16_t)v.w;
      out8[idx] = t;
    }
  }
}

// ---- main: persistent 8-layer MLP chain, activations in LDS ----
// 256 blocks (1/CU), 1024 threads = 16 waves in a 4x4 (m-strip x g-strip) grid.
// Wave owns 32 m-rows x 128 g-cols via 4 tiles of mfma_f32_32x32x16_bf16:
// per k-step ONE Y b128 read (B-operand, reused by 4 g-tiles) + 4 W b128
// global loads (A-operand). LDS read traffic: 512 KB/CU/layer (8x less than
// round 2). Register double-buffer W+Y; at ks==31 prefetch next layer's W[0]
// so the global pipe stays busy across both barriers.
template <bool PREP>
__global__ __launch_bounds__(1024, 4) void fused_mlp(
    const float* __restrict__ x,
    const bf16_t* __restrict__ WbigT, const bf16_t* __restrict__ WlilT,
    const float* __restrict__ WbigF, const float* __restrict__ WlilF,
    const float* __restrict__ Bbig, const float* __restrict__ Blil,
    float* __restrict__ out) {
  __shared__ alignas(16) bf16_t Y[TM * F];  // 128 KB, XOR-swizzled 16B chunks

  const int tid = threadIdx.x;
  const int lane = tid & 63;
  const int wave = tid >> 6;      // 0..15
  const int ml = lane & 31;       // row within strip (A: g-local, B/D: m-local)
  const int h = lane >> 5;        // half-wave: k offset 8*h
  const int gs = wave & 3;        // g-strip
  const int ms = wave >> 2;       // m-strip
  const int g0 = gs * 128;
  const int m = ms * 32 + ml;     // block-local row this lane reads/writes
  const int msw = ml & 7;         // swizzle key (low bits of m)

  // XCD-aware block->(model,row_block)
  const int bid = blockIdx.x;
  const int xcd = bid & 7;
  const int slot = bid >> 3;
  int model, rb;
  if (slot < 16) { model = 1 + xcd; rb = slot; }
  else           { model = 0; rb = (xcd << 4) + (slot - 16); }
  const size_t grow = (model == 0) ? (size_t)rb * TM
                                   : (size_t)(16384 + (model - 1) * 2048 + rb * TM);

  // per-model W/bias bases and layer strides
  const bf16_t* Wt0 = nullptr;
  const float* Wf0 = nullptr;
  if (PREP) {
    Wt0 = (model == 0) ? WbigT : WlilT + (size_t)(model - 1) * F * F;
  } else {
    Wf0 = (model == 0) ? WbigF : WlilF + (size_t)(model - 1) * F * F;
  }
  const size_t wstride = (model == 0) ? (size_t)F * F : (size_t)NLIL * F * F;
  const float* B0 = (model == 0) ? Bbig : Blil + (size_t)(model - 1) * F;
  const size_t bstride = (model == 0) ? F : (size_t)NLIL * F;

  bf16x8 wcur[4], wnxt[4], ycur, ynxt;

  // W loader: A-frag for 32x32x16 = W^T[g = g0+t*32+ml][k0 .. k0+7], k0=ks*16+h*8
  auto loadW = [&](const bf16_t* Wt, const float* Wf, int ks, bf16x8* dst) {
    const int k0 = ks * 16 + h * 8;
    if (PREP) {
#pragma unroll
      for (int t = 0; t < 4; ++t)
        dst[t] = *(const bf16x8*)&Wt[(size_t)(g0 + t * 32 + ml) * F + k0];
    } else if (model != 0) {
#pragma unroll
      for (int t = 0; t < 4; ++t) {
        const float* p = Wf + (size_t)(g0 + t * 32 + ml) * F + k0;
        float4 u = *(const float4*)p;
        float4 v = *(const float4*)(p + 4);
        bf16x8 tt;
        tt[0] = (bf16_t)u.x; tt[1] = (bf16_t)u.y; tt[2] = (bf16_t)u.z; tt[3] = (bf16_t)u.w;
        tt[4] = (bf16_t)v.x; tt[5] = (bf16_t)v.y; tt[6] = (bf16_t)v.z; tt[7] = (bf16_t)v.w;
        dst[t] = tt;
      }
    } else {
#pragma unroll
      for (int t = 0; t < 4; ++t) {
        int col = g0 + t * 32 + ml;
        bf16x8 tt;
#pragma unroll
        for (int j = 0; j < 8; ++j) tt[j] = (bf16_t)Wf[(size_t)(k0 + j) * F + col];
        dst[t] = tt;
      }
    }
  };
  // Y loader: B-frag = Y[m][k0..k0+7] through the XOR chunk swizzle
  auto loadY = [&](int ks) -> bf16x8 {
    return *(const bf16x8*)&Y[m * F + (((ks * 2 + h) ^ msw) << 3)];
  };

  // prefetch W for layer 0, ks 0 (overlaps with x staging below)
  loadW(Wt0, Wf0, 0, wcur);

  // ---- stage x tile (fp32 global) into LDS as bf16 (swizzled) ----
  {
    const float4* xs = (const float4*)(x + grow * F);
#pragma unroll
    for (int i = 0; i < 16; ++i) {
      int f4 = tid + i * 1024;  // 0..16383
      int row = f4 >> 7;
      int c4 = f4 & 127;
      float4 v = xs[f4];
      bf16x4 o;
      o[0] = (bf16_t)v.x; o[1] = (bf16_t)v.y; o[2] = (bf16_t)v.z; o[3] = (bf16_t)v.w;
      int k = c4 * 4;
      *(bf16x4*)&Y[row * F + ((((k >> 3) ^ (row & 7)) << 3) | (k & 7))] = o;
    }
  }
  __syncthreads();
  ycur = loadY(0);

  for (int l = 0; l < NLAYERS; ++l) {
    const bf16_t* Wt = PREP ? Wt0 + (size_t)l * wstride : nullptr;
    const float* Wf = PREP ? nullptr : Wf0 + (size_t)l * wstride;
    const int ln = (l + 1 < NLAYERS) ? l + 1 : l;
    const bf16_t* WtN = PREP ? Wt0 + (size_t)ln * wstride : nullptr;
    const float* WfN = PREP ? nullptr : Wf0 + (size_t)ln * wstride;
    const float* Bp = B0 + (size_t)l * bstride;

    // acc init from bias: D row axis is g; lane's g = t*32 + 8*qd + 4*h + r
    f32x16 acc[4];
#pragma unroll
    for (int t = 0; t < 4; ++t)
#pragma unroll
      for (int qd = 0; qd < 4; ++qd) {
        f32x4 bv = *(const f32x4*)&Bp[g0 + t * 32 + qd * 8 + h * 4];
#pragma unroll
        for (int r = 0; r < 4; ++r) acc[t][qd * 4 + r] = bv[r];
      }

#pragma unroll 2
    for (int ks = 0; ks < 32; ++ks) {
      if (ks < 31) {
        loadW(Wt, Wf, ks + 1, wnxt);
        ynxt = loadY(ks + 1);
      } else {
        loadW(WtN, WfN, 0, wnxt);  // cross-barrier prefetch of next layer
        ynxt = ycur;
      }
#pragma unroll
      for (int t = 0; t < 4; ++t)
        acc[t] = __builtin_amdgcn_mfma_f32_32x32x16_bf16(wcur[t], ycur, acc[t], 0, 0, 0);
#pragma unroll
      for (int t = 0; t < 4; ++t) wcur[t] = wnxt[t];
      ycur = ynxt;
    }
    __syncthreads();  // all waves done reading Y

    if (l < NLAYERS - 1) {
      // D: col = lane&31 (m-local), row = (reg&3)+8*(reg>>2)+4h (g-local)
      // quad qd (regs 4qd..4qd+3) = 4 consecutive g -> one ds_write_b64
#pragma unroll
      for (int t = 0; t < 4; ++t)
#pragma unroll
        for (int qd = 0; qd < 4; ++qd) {
          int gb = g0 + t * 32 + qd * 8 + h * 4;  // gb%8 in {0,4}
          bf16x4 t4;
#pragma unroll
          for (int r = 0; r < 4; ++r) t4[r] = (bf16_t)acc[t][qd * 4 + r];
          *(bf16x4*)&Y[m * F + ((((gb >> 3) ^ msw) << 3) | (gb & 7))] = t4;
        }
      __syncthreads();
      ycur = loadY(0);
    } else {
      float* op = out + grow * F;
#pragma unroll
      for (int t = 0; t < 4; ++t)
#pragma unroll
        for (int qd = 0; qd < 4; ++qd) {
          int gb = g0 + t * 32 + qd * 8 + h * 4;
          f32x4 v;
#pragma unroll
          for (int r = 0; r < 4; ++r) v[r] = acc[t][qd * 4 + r];
          *(f32x4*)&op[(size_t)m * F + gb] = v;
        }
    }
  }
}

extern "C" void kernel_launch(void* const* d_in, const int* in_sizes, int n_in,
                              void* d_out, int out_size, void* d_ws, size_t ws_size,
                              hipStream_t stream) {
  const float* x    = (const float*)d_in[0];
  const float* Wbig = (const float*)d_in[1];
  const float* Bbig = (const float*)d_in[2];
  const float* Wlil = (const float*)d_in[3];
  const float* Blil = (const float*)d_in[4];
  float* out = (float*)d_out;

  const size_t nWbig = (size_t)NLAYERS * F * F;         // 2,097,152
  const size_t nWlil = (size_t)NLAYERS * NLIL * F * F;  // 16,777,216
  const size_t need = (nWbig + nWlil) * sizeof(bf16_t); // ~36 MB

  if (ws_size >= need) {
    bf16_t* WbigT = (bf16_t*)d_ws;
    bf16_t* WlilB = WbigT + nWbig;
    prep_w<<<1024, 256, 0, stream>>>(Wbig, Wlil, WbigT, WlilB);
    fused_mlp<true><<<256, 1024, 0, stream>>>(x, WbigT, WlilB, nullptr, nullptr,
                                              Bbig, Blil, out);
  } else {
    fused_mlp<false><<<256, 1024, 0, stream>>>(x, nullptr, nullptr, Wbig, Wlil,
                                               Bbig, Blil, out);
  }
}